// Round 7
// baseline (240.281 us; speedup 1.0000x reference)
//
#include <hip/hip_runtime.h>

#define KK 21
#define HH 512
#define WW 512
#define CC 3
#define BB 32
#define NBC (BB * CC)
#define TILE_Y 64
#define TILE_X 128
#define SROWS 85        // 2-kh packing reads rows up to 16*3+15+2*10+1 = 84
#define SSTRIDE 168     // ushort elems/row = 21 chunks * 8; linear for DMA dest
#define NKHP 11         // ceil(21/2) kh-pairs; kh=21 is a zero row in B
#define NB_PER_B (NKHP * 3 * 512)   // 16896 bf16 elems per batch
#define NBLK (NBC * 32)             // 3072 blocks

// ---- padded bf16 image (pre-pass output) ----
// px[r][col] = bf16(x[r-10][col-12]) or 0;  r in [0,533), col in [0,560)
// covers gy in [-10,522], gx in [-12,547]; all staged chunks 16B-aligned.
#define PW 560
#define PH 533
#define PCHUNK 70                         // 16B chunks per padded row
#define PAD_PER_BC ((size_t)PH * PW)      // ushort elems per image-channel
#define CPB (PH * PCHUNK)                 // 37310 chunks per bc
#define PADBLK_PER_BC 146                 // ceil(37310/256)
#define B_ELEMS ((size_t)BB * NB_PER_B)
#define B_BYTES (B_ELEMS * 2)             // 1,081,344 (16B-aligned)
#define WS_NEED (B_BYTES + (size_t)NBC * PAD_PER_BC * 2)
#define NDMA (SROWS * 21)                 // 1785 16B chunks staged per tile
#define NCHUNK_FB 20                      // fallback staging chunks per row

typedef __attribute__((ext_vector_type(8))) short short8;
typedef __attribute__((ext_vector_type(4))) float floatx4;

__device__ __forceinline__ unsigned short f2bf(float f) {
    union { float f; unsigned u; } v; v.f = f;
    unsigned r = v.u + 0x7FFF + ((v.u >> 16) & 1);   // RNE
    return (unsigned short)(r >> 16);
}

__device__ __forceinline__ void dma16(const unsigned short* g, unsigned short* l) {
    __builtin_amdgcn_global_load_lds(
        (const __attribute__((address_space(1))) unsigned int*)g,
        (__attribute__((address_space(3))) unsigned int*)l, 16, 0, 0);
}

// ---- kernel 1: build banded-Toeplitz B fragments (2 kernel rows packed per K=32) ----
// el = khp*1536 + half*512 + (q*16 + n)*8 + j   (bf16)
// k = q*8+j; h = k>>4 (selects kernel row 2*khp+h); c = k&15
// tap d = c - n - 2 + 16*half  (staged origin gx = tx0 - 12 + lc)
__global__ __launch_bounds__(256) void build_B(
    const float* __restrict__ ker, unsigned short* __restrict__ wsB)
{
    const int b = blockIdx.x;
    const float* __restrict__ kp = ker + b * KK * KK;
    unsigned short* __restrict__ wb = wsB + (size_t)b * NB_PER_B;
    for (int e = threadIdx.x; e < NB_PER_B; e += 256) {
        const int j    = e & 7;
        const int n    = (e >> 3) & 15;
        const int q    = (e >> 7) & 3;
        const int f    = e >> 9;           // khp*3 + half
        const int khp  = f / 3;
        const int half = f - khp * 3;
        const int k    = q * 8 + j;
        const int h    = k >> 4;
        const int c    = k & 15;
        const int kh   = 2 * khp + h;
        const int d    = c - n - 2 + 16 * half;
        float v = 0.0f;
        if (kh < KK && d >= 0 && d < KK) v = kp[kh * KK + d];
        wb[e] = f2bf(v);
    }
}

// ---- kernel 1b: padded bf16 pre-pass (f32 NCHW -> zero-padded bf16) ----
__global__ __launch_bounds__(256) void pad_bf16(
    const float* __restrict__ x, unsigned short* __restrict__ px)
{
    const int bc = blockIdx.x / PADBLK_PER_BC;
    const int i  = (blockIdx.x % PADBLK_PER_BC) * 256 + threadIdx.x;
    if (i >= CPB) return;
    const int r   = i / PCHUNK;
    const int c   = i - r * PCHUNK;
    const int gy  = r - 10;
    const int gx0 = 8 * c - 12;
    float4 v0 = make_float4(0.f, 0.f, 0.f, 0.f);
    float4 v1 = make_float4(0.f, 0.f, 0.f, 0.f);
    if (gy >= 0 && gy < HH) {
        const float* __restrict__ rp = x + (size_t)bc * HH * WW + (size_t)gy * WW;
        if (gx0 >= 0 && gx0 + 7 < WW) {
            v0 = *(const float4*)(rp + gx0);
            v1 = *(const float4*)(rp + gx0 + 4);
        } else {
            if (gx0 + 0 >= 0 && gx0 + 0 < WW) v0.x = rp[gx0 + 0];
            if (gx0 + 1 >= 0 && gx0 + 1 < WW) v0.y = rp[gx0 + 1];
            if (gx0 + 2 >= 0 && gx0 + 2 < WW) v0.z = rp[gx0 + 2];
            if (gx0 + 3 >= 0 && gx0 + 3 < WW) v0.w = rp[gx0 + 3];
            if (gx0 + 4 >= 0 && gx0 + 4 < WW) v1.x = rp[gx0 + 4];
            if (gx0 + 5 >= 0 && gx0 + 5 < WW) v1.y = rp[gx0 + 5];
            if (gx0 + 6 >= 0 && gx0 + 6 < WW) v1.z = rp[gx0 + 6];
            if (gx0 + 7 >= 0 && gx0 + 7 < WW) v1.w = rp[gx0 + 7];
        }
    }
    const int p0 = (int)((unsigned)f2bf(v0.x) | ((unsigned)f2bf(v0.y) << 16));
    const int p1 = (int)((unsigned)f2bf(v0.z) | ((unsigned)f2bf(v0.w) << 16));
    const int p2 = (int)((unsigned)f2bf(v1.x) | ((unsigned)f2bf(v1.y) << 16));
    const int p3 = (int)((unsigned)f2bf(v1.z) | ((unsigned)f2bf(v1.w) << 16));
    *(int4*)(px + (size_t)bc * PAD_PER_BC + (size_t)r * PW + 8 * c) = make_int4(p0, p1, p2, p3);
}

// ---- kernel 2: main MFMA conv; staging = pure global_load_lds DMA ----
__global__ __launch_bounds__(256, 5) void dwconv_mfma(
    const unsigned short* __restrict__ px,
    const unsigned short* __restrict__ wsB,
    float* __restrict__ out)
{
    __shared__ __align__(16) unsigned short s_in[SROWS * SSTRIDE];  // 28560 B

    const int bc  = blockIdx.x >> 5;          // 0..95
    const int t   = blockIdx.x & 31;
    const int ty0 = (t >> 2) * TILE_Y;
    const int tx0 = (t & 3) * TILE_X;
    const int b   = bc / CC;
    const int tid = threadIdx.x;

    // ---- stage 85x168 bf16 window via DMA: 7 wave-instrs, no VALU/regs ----
    // chunk i: row ly=i/21, chunk c=i%21; LDS dest = 16*i (linear per lane)
    const unsigned short* __restrict__ pb =
        px + (size_t)bc * PAD_PER_BC + (size_t)ty0 * PW + tx0;
#pragma unroll
    for (int k = 0; k < 7; ++k) {
        const int i = tid + 256 * k;
        if (k < 6 || i < NDMA) {              // 1785 = 256*6 + 249
            const int ly = i / 21;
            const int c  = i - ly * 21;
            dma16(pb + (size_t)ly * PW + 8 * c, s_in + 8 * i);
        }
    }
    __syncthreads();   // compiler drains vmcnt(0) before the barrier

    const int lane = tid & 63;
    const int wv   = tid >> 6;       // wave 0..3 -> output rows 16*wv..+15
    const int mrow = lane & 15;      // A's m / B's n / D's col
    const int qd   = lane >> 4;      // k-chunk: h = qd>>1 (kernel row), col half = qd&1

    floatx4 acc[8];
#pragma unroll
    for (int tt = 0; tt < 8; ++tt) acc[tt] = (floatx4){0.f, 0.f, 0.f, 0.f};

    const unsigned short* bbase = wsB + (size_t)b * NB_PER_B + lane * 8;
    const unsigned short* abase = s_in + ((16 * wv + mrow + (qd >> 1)) * SSTRIDE) + 8 * (qd & 1);

    short8 nb1 = *(const short8*)(bbase);
    short8 nb2 = *(const short8*)(bbase + 512);
    short8 nb3 = *(const short8*)(bbase + 1024);

#pragma unroll 1
    for (int khp = 0; khp < NKHP; ++khp) {
        const short8 b1 = nb1;
        const short8 b2 = nb2;
        const short8 b3 = nb3;
        const int khn = (khp < NKHP - 1) ? (khp + 1) : khp;   // clamped prefetch
        nb1 = *(const short8*)(bbase + khn * 1536);
        nb2 = *(const short8*)(bbase + khn * 1536 + 512);
        nb3 = *(const short8*)(bbase + khn * 1536 + 1024);

        const unsigned short* arow = abase + 2 * khp * SSTRIDE;
        short8 a[10];
#pragma unroll
        for (int s = 0; s < 10; ++s) a[s] = *(const short8*)(arow + 16 * s);

#pragma unroll
        for (int tt = 0; tt < 8; ++tt) {
            acc[tt] = __builtin_amdgcn_mfma_f32_16x16x32_bf16(a[tt],     b1, acc[tt], 0, 0, 0);
            acc[tt] = __builtin_amdgcn_mfma_f32_16x16x32_bf16(a[tt + 1], b2, acc[tt], 0, 0, 0);
            acc[tt] = __builtin_amdgcn_mfma_f32_16x16x32_bf16(a[tt + 2], b3, acc[tt], 0, 0, 0);
        }
    }

    // ---- epilogue: D layout col=lane&15, row=(lane>>4)*4+reg ----
    float* __restrict__ op = out + (size_t)bc * HH * WW;
#pragma unroll
    for (int tt = 0; tt < 8; ++tt) {
#pragma unroll
        for (int r = 0; r < 4; ++r) {
            const int y = ty0 + 16 * wv + qd * 4 + r;
            const int xcol = tx0 + 16 * tt + mrow;
            op[(size_t)y * WW + xcol] = acc[tt][r];
        }
    }
}

// ---- fallback conv (R5 structure, reg staging) for small workspaces ----
__global__ __launch_bounds__(256, 5) void dwconv_mfma_fb(
    const float* __restrict__ x,
    const unsigned short* __restrict__ wsB,
    float* __restrict__ out)
{
    __shared__ __align__(16) unsigned short s_in[SROWS * SSTRIDE];

    const int bc  = blockIdx.x >> 5;
    const int t   = blockIdx.x & 31;
    const int ty0 = (t >> 2) * TILE_Y;
    const int tx0 = (t & 3) * TILE_X;
    const int b   = bc / CC;
    const float* __restrict__ xp = x + (size_t)bc * HH * WW;
    const int tid = threadIdx.x;

    for (int i = tid; i < SROWS * NCHUNK_FB; i += 256) {
        const int ly  = i / NCHUNK_FB;
        const int k   = i - ly * NCHUNK_FB;
        const int gy  = ty0 - 10 + ly;
        const int gx0 = tx0 - 12 + 8 * k;
        float4 v0 = make_float4(0.f, 0.f, 0.f, 0.f);
        float4 v1 = make_float4(0.f, 0.f, 0.f, 0.f);
        if (gy >= 0 && gy < HH) {
            const float* __restrict__ rp = xp + (size_t)gy * WW;
            if (gx0 >= 0 && gx0 + 7 < WW) {
                v0 = *(const float4*)(rp + gx0);
                v1 = *(const float4*)(rp + gx0 + 4);
            } else {
                if (gx0 + 0 >= 0 && gx0 + 0 < WW) v0.x = rp[gx0 + 0];
                if (gx0 + 1 >= 0 && gx0 + 1 < WW) v0.y = rp[gx0 + 1];
                if (gx0 + 2 >= 0 && gx0 + 2 < WW) v0.z = rp[gx0 + 2];
                if (gx0 + 3 >= 0 && gx0 + 3 < WW) v0.w = rp[gx0 + 3];
                if (gx0 + 4 >= 0 && gx0 + 4 < WW) v1.x = rp[gx0 + 4];
                if (gx0 + 5 >= 0 && gx0 + 5 < WW) v1.y = rp[gx0 + 5];
                if (gx0 + 6 >= 0 && gx0 + 6 < WW) v1.z = rp[gx0 + 6];
                if (gx0 + 7 >= 0 && gx0 + 7 < WW) v1.w = rp[gx0 + 7];
            }
        }
        const int p0 = (int)((unsigned)f2bf(v0.x) | ((unsigned)f2bf(v0.y) << 16));
        const int p1 = (int)((unsigned)f2bf(v0.z) | ((unsigned)f2bf(v0.w) << 16));
        const int p2 = (int)((unsigned)f2bf(v1.x) | ((unsigned)f2bf(v1.y) << 16));
        const int p3 = (int)((unsigned)f2bf(v1.z) | ((unsigned)f2bf(v1.w) << 16));
        *(int4*)&s_in[ly * SSTRIDE + 8 * k] = make_int4(p0, p1, p2, p3);
    }
    __syncthreads();

    const int lane = tid & 63;
    const int wv   = tid >> 6;
    const int mrow = lane & 15;
    const int qd   = lane >> 4;

    floatx4 acc[8];
#pragma unroll
    for (int tt = 0; tt < 8; ++tt) acc[tt] = (floatx4){0.f, 0.f, 0.f, 0.f};

    const unsigned short* bbase = wsB + (size_t)b * NB_PER_B + lane * 8;
    const unsigned short* abase = s_in + ((16 * wv + mrow + (qd >> 1)) * SSTRIDE) + 8 * (qd & 1);

    short8 nb1 = *(const short8*)(bbase);
    short8 nb2 = *(const short8*)(bbase + 512);
    short8 nb3 = *(const short8*)(bbase + 1024);

#pragma unroll 1
    for (int khp = 0; khp < NKHP; ++khp) {
        const short8 b1 = nb1;
        const short8 b2 = nb2;
        const short8 b3 = nb3;
        const int khn = (khp < NKHP - 1) ? (khp + 1) : khp;
        nb1 = *(const short8*)(bbase + khn * 1536);
        nb2 = *(const short8*)(bbase + khn * 1536 + 512);
        nb3 = *(const short8*)(bbase + khn * 1536 + 1024);

        const unsigned short* arow = abase + 2 * khp * SSTRIDE;
        short8 a[10];
#pragma unroll
        for (int s = 0; s < 10; ++s) a[s] = *(const short8*)(arow + 16 * s);

#pragma unroll
        for (int tt = 0; tt < 8; ++tt) {
            acc[tt] = __builtin_amdgcn_mfma_f32_16x16x32_bf16(a[tt],     b1, acc[tt], 0, 0, 0);
            acc[tt] = __builtin_amdgcn_mfma_f32_16x16x32_bf16(a[tt + 1], b2, acc[tt], 0, 0, 0);
            acc[tt] = __builtin_amdgcn_mfma_f32_16x16x32_bf16(a[tt + 2], b3, acc[tt], 0, 0, 0);
        }
    }

    float* __restrict__ op = out + (size_t)bc * HH * WW;
#pragma unroll
    for (int tt = 0; tt < 8; ++tt) {
#pragma unroll
        for (int r = 0; r < 4; ++r) {
            const int y = ty0 + 16 * wv + qd * 4 + r;
            const int xcol = tx0 + 16 * tt + mrow;
            op[(size_t)y * WW + xcol] = acc[tt][r];
        }
    }
}

extern "C" void kernel_launch(void* const* d_in, const int* in_sizes, int n_in,
                              void* d_out, int out_size, void* d_ws, size_t ws_size,
                              hipStream_t stream) {
    const float* x   = (const float*)d_in[0];
    const float* ker = (const float*)d_in[1];
    float* out = (float*)d_out;
    unsigned short* wsB = (unsigned short*)d_ws;

    build_B<<<BB, 256, 0, stream>>>(ker, wsB);

    if (ws_size >= WS_NEED) {
        unsigned short* px = wsB + B_ELEMS;   // byte offset 1,081,344 (16B-aligned)
        pad_bf16<<<NBC * PADBLK_PER_BC, 256, 0, stream>>>(x, px);
        dwconv_mfma<<<NBLK, 256, 0, stream>>>(px, wsB, out);
    } else {
        dwconv_mfma_fb<<<NBLK, 256, 0, stream>>>(x, wsB, out);
    }
}